// Round 9
// baseline (10660.197 us; speedup 1.0000x reference)
//
#include <hip/hip_runtime.h>

#define V_ 32000
#define E_ 256
#define H_ 512
#define B_ 32
#define S_ 128
#define T_ 64
#define TD_ 63        // decoder steps (T-1)
#define G3_ 1536      // 3*H
#define CATK_ 1792    // H + E + 2H
#define DIN_ 1280     // E + 2H
#define MPAD_ 2048    // padded M for fc1 MFMA

typedef __attribute__((ext_vector_type(8))) short bf16x8;
typedef __attribute__((ext_vector_type(4))) float f32x4;

__device__ inline unsigned short bf16_rne(float x) {
    unsigned u = __float_as_uint(x);
    unsigned r = u + 0x7FFFu + ((u >> 16) & 1u);
    return (unsigned short)(r >> 16);
}

// agent-scope ops: coherence-point access, no cache invalidation (r5-proven)
__device__ __forceinline__ float ato_ldf(const float* p) {
    return __hip_atomic_load((const float*)p, __ATOMIC_RELAXED, __HIP_MEMORY_SCOPE_AGENT);
}
__device__ __forceinline__ void ato_stf(float* p, float v) {
    __hip_atomic_store(p, v, __ATOMIC_RELAXED, __HIP_MEMORY_SCOPE_AGENT);
}

// ---------------------------------------------------------------------------
// Fence-free hierarchical barrier: groups of 16 blocks + top level.
// ---------------------------------------------------------------------------
__device__ __forceinline__ void fast_barN(unsigned* base, int idx, unsigned ngroups)
{
    asm volatile("s_waitcnt vmcnt(0)" ::: "memory");
    __syncthreads();
    if (threadIdx.x == 0) {
        unsigned* gcnt = base + (idx >> 4) * 64;
        unsigned* ggen = gcnt + 32;
        unsigned* tcnt = base + ngroups * 64;
        unsigned* tgen = tcnt + 32;
        unsigned g0 = __hip_atomic_load(ggen, __ATOMIC_RELAXED, __HIP_MEMORY_SCOPE_AGENT);
        unsigned a  = __hip_atomic_fetch_add(gcnt, 1u, __ATOMIC_RELAXED, __HIP_MEMORY_SCOPE_AGENT);
        if (a == 15u) {
            unsigned t0 = __hip_atomic_load(tgen, __ATOMIC_RELAXED, __HIP_MEMORY_SCOPE_AGENT);
            unsigned ta = __hip_atomic_fetch_add(tcnt, 1u, __ATOMIC_RELAXED, __HIP_MEMORY_SCOPE_AGENT);
            if (ta == ngroups - 1u) {
                __hip_atomic_store(tcnt, 0u, __ATOMIC_RELAXED, __HIP_MEMORY_SCOPE_AGENT);
                __hip_atomic_store(tgen, t0 + 1u, __ATOMIC_RELAXED, __HIP_MEMORY_SCOPE_AGENT);
            } else {
                while (__hip_atomic_load(tgen, __ATOMIC_RELAXED, __HIP_MEMORY_SCOPE_AGENT) == t0)
                    __builtin_amdgcn_s_sleep(1);
            }
            __hip_atomic_store(gcnt, 0u, __ATOMIC_RELAXED, __HIP_MEMORY_SCOPE_AGENT);
            __hip_atomic_store(ggen, g0 + 1u, __ATOMIC_RELAXED, __HIP_MEMORY_SCOPE_AGENT);
        } else {
            while (__hip_atomic_load(ggen, __ATOMIC_RELAXED, __HIP_MEMORY_SCOPE_AGENT) == g0)
                __builtin_amdgcn_s_sleep(1);
        }
    }
    __syncthreads();
}

// ---------------------------------------------------------------------------
__global__ __launch_bounds__(256)
void prep_kernel(const int* __restrict__ src, const int* __restrict__ tgt,
                 int* __restrict__ tokf, int* __restrict__ tokb, int* __restrict__ tokd,
                 float* __restrict__ h_enc, unsigned* __restrict__ bars)
{
    int tid = blockIdx.x * 256 + threadIdx.x;
    if (tid < S_ * B_) {
        int s = tid >> 5, b = tid & 31;
        tokf[tid] = src[b * S_ + s];
        tokb[tid] = src[b * S_ + (S_ - 1 - s)];
    }
    if (tid < TD_ * B_) {
        int t = tid >> 5, b = tid & 31;
        tokd[tid] = tgt[b * T_ + t];
    }
    if (tid < 2 * 2 * B_ * H_) h_enc[tid] = 0.f;   // all 4 h_enc slots
    if (tid < 4096) bars[tid] = 0u;
}

// ---------------------------------------------------------------------------
__global__ __launch_bounds__(256)
void emb_cat_kernel(const int* __restrict__ tokd, const float* __restrict__ dec_emb,
                    float* __restrict__ cat)
{
    int row = blockIdx.x;          // row = t*32 + b
    int tid = threadIdx.x;         // 0..255 == E_
    cat[(size_t)row * CATK_ + H_ + tid] = dec_emb[(size_t)tokd[row] * E_ + tid];
}

// ---------------------------------------------------------------------------
// Generic fp32 GEMM (small GEMMs + fallback fc1)
// ---------------------------------------------------------------------------
template<int GATHER, int FC1MAP>
__global__ __launch_bounds__(256)
void gemm128_kernel(const float* __restrict__ A, int lda,
                    const int* __restrict__ tokens, const float* __restrict__ emb,
                    const float* __restrict__ W, int ldw,
                    const float* __restrict__ bias,
                    float* __restrict__ C, int ldc,
                    int M, int N, int K)
{
    __shared__ float As[16][132];
    __shared__ float Ws[16][132];
    (void)N;
    int tid = threadIdx.x;
    int m0 = blockIdx.y * 128, n0 = blockIdx.x * 128;
    int tx = tid & 15, ty = tid >> 4;
    float c[8][8];
#pragma unroll
    for (int i = 0; i < 8; i++)
#pragma unroll
        for (int j = 0; j < 8; j++) c[i][j] = 0.f;

    int arow = tid >> 1;
    int kq = (tid & 1) * 8;

    int am = m0 + arow; if (am >= M) am = M - 1;
    const float* arp;
    if (GATHER) arp = emb + (size_t)tokens[am] * (size_t)K;
    else        arp = A + (size_t)am * (size_t)lda;
    const float* wrp = W + (size_t)(n0 + arow) * (size_t)ldw;

    for (int kb = 0; kb < K; kb += 16) {
        __syncthreads();
        float4 a0 = *(const float4*)(arp + kb + kq);
        float4 a1 = *(const float4*)(arp + kb + kq + 4);
        float4 w0 = *(const float4*)(wrp + kb + kq);
        float4 w1 = *(const float4*)(wrp + kb + kq + 4);
        As[kq + 0][arow] = a0.x; As[kq + 1][arow] = a0.y;
        As[kq + 2][arow] = a0.z; As[kq + 3][arow] = a0.w;
        As[kq + 4][arow] = a1.x; As[kq + 5][arow] = a1.y;
        As[kq + 6][arow] = a1.z; As[kq + 7][arow] = a1.w;
        Ws[kq + 0][arow] = w0.x; Ws[kq + 1][arow] = w0.y;
        Ws[kq + 2][arow] = w0.z; Ws[kq + 3][arow] = w0.w;
        Ws[kq + 4][arow] = w1.x; Ws[kq + 5][arow] = w1.y;
        Ws[kq + 6][arow] = w1.z; Ws[kq + 7][arow] = w1.w;
        __syncthreads();
#pragma unroll
        for (int kk = 0; kk < 16; kk++) {
            float a[8], bb[8];
            *(float4*)&a[0]  = *(const float4*)&As[kk][ty * 8];
            *(float4*)&a[4]  = *(const float4*)&As[kk][ty * 8 + 4];
            *(float4*)&bb[0] = *(const float4*)&Ws[kk][tx * 8];
            *(float4*)&bb[4] = *(const float4*)&Ws[kk][tx * 8 + 4];
#pragma unroll
            for (int i = 0; i < 8; i++)
#pragma unroll
                for (int j = 0; j < 8; j++) c[i][j] += a[i] * bb[j];
        }
    }

#pragma unroll
    for (int i = 0; i < 8; i++) {
        int m = m0 + ty * 8 + i;
        if (m < M) {
            size_t rowoff;
            if (FC1MAP) { int tt = m >> 5, bb2 = m & 31; rowoff = ((size_t)bb2 * T_ + tt) * (size_t)ldc; }
            else        rowoff = (size_t)m * (size_t)ldc;
#pragma unroll
            for (int j = 0; j < 8; j += 4) {
                int n = n0 + tx * 8 + j;
                float4 v;
                v.x = c[i][j + 0] + bias[n + 0];
                v.y = c[i][j + 1] + bias[n + 1];
                v.z = c[i][j + 2] + bias[n + 2];
                v.w = c[i][j + 3] + bias[n + 3];
                *(float4*)(C + rowoff + n) = v;
            }
        }
    }
}

// ---------------------------------------------------------------------------
// PERSISTENT bi-GRU encoder v9: 128 blocks = (bp 16) x (dir 2) x (kr 4).
// bid = bp*8 + dir*4 + kr  ->  XCD = bid%8 = dir*4+kr: all 16 same-(dir,kr)
// blocks on one XCD -> their 384-row Whh slice (768 KB) stays L2-resident.
// Block owns batches {2bp, 2bp+1} x k-range [kr*128, +128).
// Per step: read h[b][:] (2 KB x2, atomics), 384 row-dots (dual-b), gates,
// write h' + enc_bt. Per-dir 64-block barrier.
// ---------------------------------------------------------------------------
__global__ __launch_bounds__(256)
void enc_coop_kernel(const float* __restrict__ gxf, const float* __restrict__ gxb,
                     const float* __restrict__ Whh_f, const float* __restrict__ bhh_f,
                     const float* __restrict__ Whh_b, const float* __restrict__ bhh_b,
                     float* __restrict__ h_enc, float* __restrict__ enc_bt,
                     const float* __restrict__ fcW, const float* __restrict__ fcb,
                     float* __restrict__ hT0, unsigned* __restrict__ bars)
{
    const int bid = blockIdx.x, tid = threadIdx.x;
    const int bp = bid >> 3, dir = (bid >> 2) & 1, kr = bid & 3;
    const int b0 = bp * 2, b1 = b0 + 1;
    const int k0 = kr * 128;
    const float* Whh = dir ? Whh_b : Whh_f;
    const float* bhh = dir ? bhh_b : bhh_f;
    const float* gx  = dir ? gxb : gxf;
    __shared__ float hA[512], hB[512];
    __shared__ float eg[3][2][128];
    __shared__ float hc2[1024];
    unsigned* dbar = bars + dir * 512;
    const int idx = bp * 4 + kr;   // 0..63 within dir

    for (int t = 0; t < S_; ++t) {
        const int pp = t & 1;
        const float* hin = h_enc + (size_t)(dir * 2 + pp) * B_ * H_;
        float* hout = h_enc + (size_t)(dir * 2 + 1 - pp) * B_ * H_;
        for (int j = tid; j < H_; j += 256) {
            hA[j] = ato_ldf(hin + (size_t)b0 * H_ + j);
            hB[j] = ato_ldf(hin + (size_t)b1 * H_ + j);
        }
        __syncthreads();
        // pass1: gates r,z (256 rows); pass2: gate n (128 rows)
        {
            int g = tid >> 7, kk = tid & 127;
            int grow = g * H_ + k0 + kk;
            const float* wrow = Whh + (size_t)grow * H_;
            float aA = 0.f, aB = 0.f;
            for (int j = 0; j < H_; j += 4) {
                float4 w = *(const float4*)(wrow + j);
                float4 ha = *(const float4*)&hA[j];
                float4 hb = *(const float4*)&hB[j];
                aA += w.x * ha.x + w.y * ha.y + w.z * ha.z + w.w * ha.w;
                aB += w.x * hb.x + w.y * hb.y + w.z * hb.z + w.w * hb.w;
            }
            float bb = bhh[grow];
            eg[g][0][kk] = aA + bb; eg[g][1][kk] = aB + bb;
        }
        if (tid < 128) {
            int grow = 2 * H_ + k0 + tid;
            const float* wrow = Whh + (size_t)grow * H_;
            float aA = 0.f, aB = 0.f;
            for (int j = 0; j < H_; j += 4) {
                float4 w = *(const float4*)(wrow + j);
                float4 ha = *(const float4*)&hA[j];
                float4 hb = *(const float4*)&hB[j];
                aA += w.x * ha.x + w.y * ha.y + w.z * ha.z + w.w * ha.w;
                aB += w.x * hb.x + w.y * hb.y + w.z * hb.z + w.w * hb.w;
            }
            float bb = bhh[grow];
            eg[2][0][tid] = aA + bb; eg[2][1][tid] = aB + bb;
        }
        __syncthreads();
        // gates: thread = (b2, kk)
        {
            int b2 = tid >> 7, kk = tid & 127;
            int k = k0 + kk, b = b2 ? b1 : b0;
            const float* gxr = gx + ((size_t)t * B_ + b) * G3_;
            float xr = gxr[k], xz = gxr[H_ + k], xn = gxr[2 * H_ + k];
            float hr = eg[0][b2][kk], hz = eg[1][b2][kk], hn = eg[2][b2][kk];
            float rg = 1.f / (1.f + expf(-(xr + hr)));
            float zg = 1.f / (1.f + expf(-(xz + hz)));
            float ng = tanhf(xn + rg * hn);
            float hp = b2 ? hB[k] : hA[k];
            float h2 = (1.f - zg) * ng + zg * hp;
            ato_stf(hout + (size_t)b * H_ + k, h2);
            int s_out = dir ? (S_ - 1 - t) : t;
            enc_bt[((size_t)b * S_ + s_out) * (2 * H_) + dir * H_ + k] = h2;
        }
        fast_barN(dbar, idx, 4);
    }
    fast_barN(bars + 1024, bid, 8);    // both dirs done

    // tail: hidden = tanh([hf,hb] @ fcW.T + fcb) -> hT0[b][k]
    {
        const int b2 = bid & 31, ih = bid >> 5;
        const float* hf  = h_enc + (size_t)b2 * H_;                  // dir0, pp0
        const float* hbk = h_enc + (size_t)(2 * B_ + b2) * H_;       // dir1, pp0
        for (int i = tid; i < H_; i += 256) {
            hc2[i] = ato_ldf(hf + i);
            hc2[H_ + i] = ato_ldf(hbk + i);
        }
        __syncthreads();
        if (tid < 128) {
            int i = ih * 128 + tid;
            const float* w = fcW + (size_t)i * (2 * H_);
            float acc = 0.f;
            for (int j = 0; j < 2 * H_; j += 4) {
                float4 a4 = *(const float4*)&hc2[j];
                float4 w4 = *(const float4*)(w + j);
                acc += a4.x * w4.x + a4.y * w4.y + a4.z * w4.z + a4.w * w4.w;
            }
            ato_stf(hT0 + (size_t)b2 * H_ + i, tanhf(acc + fcb[i]));
        }
    }
}

// ---------------------------------------------------------------------------
// PERSISTENT attention decoder v9: 128 blocks = (bp 16) x (kr 8).
// bid = bp*8 + kr -> XCD = kr: 16 same-kr blocks share their weight slice
// (Whh 192 rows + Wih 192 rows + W_h 64 rows ~ 1.3 MB, L2-resident).
// Block owns batches {2bp, 2bp+1} x k-range [kr*64, +64).
// P0: read h[b][:] (atomics) -> hwh rows (t<64) + ghh rows (t>=64, LDS-local).
// P1: attn for b where kr == b&7 (4 b's/XCD): softmax -> w -> wT + cat.
// P2: read w[b][:] (atomics) -> xw rows (LDS-local) -> gates -> h' + cat.
// ghh/xw NEVER leave the block. 3 barriers/step.
// ---------------------------------------------------------------------------
__global__ __launch_bounds__(256)
void dec_coop_kernel(const float* __restrict__ attn_W, const float* __restrict__ attn_v,
                     const float* __restrict__ enc_projB, const float* __restrict__ enc_bt,
                     const int* __restrict__ src,
                     const float* __restrict__ dWhh, const float* __restrict__ dbhh,
                     const float* __restrict__ dWih, const float* __restrict__ gx_emb,
                     float* __restrict__ cat, float* __restrict__ hT,
                     float* __restrict__ hwhT, float* __restrict__ wT,
                     unsigned* __restrict__ bars)
{
    const int bid = blockIdx.x, tid = threadIdx.x;
    const int bp = bid >> 3, kr = bid & 7;
    const int b0 = bp * 2, b1 = b0 + 1;
    const int k0 = kr * 64;
    __shared__ float hA[512], hB[512];
    __shared__ float ghhA[192], ghhB[192];
    __shared__ float xwA[192], xwB[192];
    __shared__ float wAB[2][1024];
    __shared__ float attnS[1168];   // hwh 512 | vL 512 | aL 128 | red @1152
    const int abn = (kr == (b0 & 7)) ? b0 : ((kr == (b1 & 7)) ? b1 : -1);

    for (int t = 0; t < TD_; ++t) {
        const int pp = t & 1;
        const float* hin = hT + (size_t)pp * (B_ * H_);
        float* hout = hT + (size_t)(1 - pp) * (B_ * H_);
        float* cat_t = cat + (size_t)t * B_ * CATK_;

        // ---- P0: h columns -> hwh (global) + ghh (LDS-local) ----
        {
            for (int j = tid; j < H_; j += 256) {
                hA[j] = ato_ldf(hin + (size_t)b0 * H_ + j);
                hB[j] = ato_ldf(hin + (size_t)b1 * H_ + j);
            }
            __syncthreads();
            if (tid < 64) {
                const float* wrow = attn_W + (size_t)(k0 + tid) * G3_;
                float aA = 0.f, aB = 0.f;
                for (int j = 0; j < H_; j += 4) {
                    float4 w = *(const float4*)(wrow + j);
                    float4 ha = *(const float4*)&hA[j];
                    float4 hb = *(const float4*)&hB[j];
                    aA += w.x * ha.x + w.y * ha.y + w.z * ha.z + w.w * ha.w;
                    aB += w.x * hb.x + w.y * hb.y + w.z * hb.z + w.w * hb.w;
                }
                ato_stf(hwhT + (size_t)b0 * H_ + k0 + tid, aA);
                ato_stf(hwhT + (size_t)b1 * H_ + k0 + tid, aB);
            } else {
                int r = tid - 64;
                int grow = (r >> 6) * H_ + k0 + (r & 63);
                const float* wrow = dWhh + (size_t)grow * H_;
                float aA = 0.f, aB = 0.f;
                for (int j = 0; j < H_; j += 4) {
                    float4 w = *(const float4*)(wrow + j);
                    float4 ha = *(const float4*)&hA[j];
                    float4 hb = *(const float4*)&hB[j];
                    aA += w.x * ha.x + w.y * ha.y + w.z * ha.z + w.w * ha.w;
                    aB += w.x * hb.x + w.y * hb.y + w.z * hb.z + w.w * hb.w;
                }
                float bb = dbhh[grow];
                ghhA[r] = aA + bb; ghhB[r] = aB + bb;
            }
        }
        fast_barN(bars, bid, 8);

        // ---- P1: attention for abn (4 blocks per XCD active) ----
        if (abn >= 0) {
            float* hwh = attnS;
            float* vL  = attnS + 512;
            float* aLs = attnS + 1024;
            float* red = attnS + 1152;
            for (int i = tid; i < H_; i += 256) {
                hwh[i] = ato_ldf(hwhT + (size_t)abn * H_ + i);
                vL[i]  = attn_v[i];
            }
            __syncthreads();
            int wv = tid >> 6, lane = tid & 63;
            for (int so = 0; so < 32; so++) {
                int s = so * 4 + wv;
                const float* pr = enc_projB + ((size_t)abn * S_ + s) * H_;
                float acc = 0.f;
#pragma unroll
                for (int u = 0; u < 8; u++) {
                    int hh = u * 64 + lane;
                    float x = hwh[hh] + pr[hh];
                    float e2 = __expf(2.f * x);
                    acc += vL[hh] * (1.f - 2.f / (e2 + 1.f));
                }
#pragma unroll
                for (int off = 1; off < 64; off <<= 1) acc += __shfl_xor(acc, off);
                if (lane == 0) aLs[s] = acc;
            }
            __syncthreads();
            if (tid < S_) aLs[tid] = (src[abn * S_ + tid] != 0) ? aLs[tid] : -1e10f;
            __syncthreads();
            if (tid < 64) {
                float m = fmaxf(aLs[tid], aLs[tid + 64]);
#pragma unroll
                for (int off = 1; off < 64; off <<= 1) m = fmaxf(m, __shfl_xor(m, off));
                if (tid == 0) red[0] = m;
            }
            __syncthreads();
            if (tid < S_) aLs[tid] = expf(aLs[tid] - red[0]);
            __syncthreads();
            if (tid < 64) {
                float sv = aLs[tid] + aLs[tid + 64];
#pragma unroll
                for (int off = 1; off < 64; off <<= 1) sv += __shfl_xor(sv, off);
                if (tid == 0) red[1] = sv;
            }
            __syncthreads();
            if (tid < S_) aLs[tid] = aLs[tid] / red[1];
            __syncthreads();
            // w[c4..c4+3] = sum_s aL[s] * enc_bt[abn][s][c]
            const int c4 = tid * 4;
            const float* eb = enc_bt + (size_t)abn * S_ * (2 * H_) + c4;
            float w0 = 0.f, w1 = 0.f, w2 = 0.f, w3 = 0.f;
            for (int s = 0; s < S_; s++) {
                float a = aLs[s];
                float4 v = *(const float4*)(eb + (size_t)s * (2 * H_));
                w0 += a * v.x; w1 += a * v.y; w2 += a * v.z; w3 += a * v.w;
            }
            ato_stf(wT + (size_t)abn * (2 * H_) + c4 + 0, w0);
            ato_stf(wT + (size_t)abn * (2 * H_) + c4 + 1, w1);
            ato_stf(wT + (size_t)abn * (2 * H_) + c4 + 2, w2);
            ato_stf(wT + (size_t)abn * (2 * H_) + c4 + 3, w3);
            float4 outv; outv.x = w0; outv.y = w1; outv.z = w2; outv.w = w3;
            *(float4*)(cat_t + (size_t)abn * CATK_ + (H_ + E_) + c4) = outv;
        }
        fast_barN(bars, bid, 8);

        // ---- P2: w columns -> xw (LDS-local) -> gates -> h' + cat ----
        {
            for (int c = tid; c < 2 * H_; c += 256) {
                wAB[0][c] = ato_ldf(wT + (size_t)b0 * (2 * H_) + c);
                wAB[1][c] = ato_ldf(wT + (size_t)b1 * (2 * H_) + c);
            }
            __syncthreads();
            if (tid < 192) {
                int grow = (tid >> 6) * H_ + k0 + (tid & 63);
                const float* wrow = dWih + (size_t)grow * DIN_ + E_;
                float aA = 0.f, aB = 0.f;
                for (int c = 0; c < 2 * H_; c += 4) {
                    float4 w = *(const float4*)(wrow + c);
                    float4 wa = *(const float4*)&wAB[0][c];
                    float4 wb = *(const float4*)&wAB[1][c];
                    aA += w.x * wa.x + w.y * wa.y + w.z * wa.z + w.w * wa.w;
                    aB += w.x * wb.x + w.y * wb.y + w.z * wb.z + w.w * wb.w;
                }
                xwA[tid] = aA; xwB[tid] = aB;
            }
            __syncthreads();
            if (tid < 128) {
                int b2 = tid >> 6, kk = tid & 63;
                int b = b2 ? b1 : b0;
                int k = k0 + kk;
                const float* gA = b2 ? ghhB : ghhA;
                const float* xA = b2 ? xwB : xwA;
                float hr = gA[kk], hz = gA[64 + kk], hn = gA[128 + kk];
                float xr = xA[kk], xz = xA[64 + kk], xn = xA[128 + kk];
                const float* gxe = gx_emb + ((size_t)t * B_ + b) * G3_;
                float rg = 1.f / (1.f + expf(-(gxe[k] + xr + hr)));
                float zg = 1.f / (1.f + expf(-(gxe[H_ + k] + xz + hz)));
                float ng = tanhf(gxe[2 * H_ + k] + xn + rg * hn);
                float hp = b2 ? hB[k] : hA[k];
                float h2 = (1.f - zg) * ng + zg * hp;
                ato_stf(hout + (size_t)b * H_ + k, h2);
                cat_t[(size_t)b * CATK_ + k] = h2;
            }
        }
        fast_barN(bars, bid, 8);
    }
}

// ---------------------------------------------------------------------------
// split cat (fp32 [2016][1792]) into bf16 hi/lo, padded to 2048 rows (zeros)
// ---------------------------------------------------------------------------
__global__ __launch_bounds__(256)
void splitA_kernel(const float* __restrict__ cat,
                   unsigned short* __restrict__ Ahi, unsigned short* __restrict__ Alo)
{
    size_t i4 = ((size_t)blockIdx.x * 256 + threadIdx.x) * 4;
    if (i4 >= (size_t)MPAD_ * CATK_) return;
    size_t row = i4 / CATK_;
    float4 v;
    if (row < (size_t)TD_ * B_) v = *(const float4*)(cat + i4);
    else { v.x = v.y = v.z = v.w = 0.f; }
    float f[4] = {v.x, v.y, v.z, v.w};
    unsigned short h[4], l[4];
#pragma unroll
    for (int j = 0; j < 4; j++) {
        h[j] = bf16_rne(f[j]);
        float hf = __uint_as_float((unsigned)h[j] << 16);
        l[j] = bf16_rne(f[j] - hf);
    }
    *(ushort4*)(Ahi + i4) = make_ushort4(h[0], h[1], h[2], h[3]);
    *(ushort4*)(Alo + i4) = make_ushort4(l[0], l[1], l[2], l[3]);
}

// ---------------------------------------------------------------------------
// fc1 via split-bf16 MFMA (hh + hl + lh): fp32-accurate logits.
// ---------------------------------------------------------------------------
__global__ __launch_bounds__(256)
void fc1_mfma_kernel(const unsigned short* __restrict__ Ahi,
                     const unsigned short* __restrict__ Alo,
                     const float* __restrict__ W,
                     const float* __restrict__ bias,
                     float* __restrict__ C)
{
    __shared__ unsigned short lA[2][128][40];
    __shared__ unsigned short lW[2][128][40];
    const int tid = threadIdx.x;
    const int m0 = blockIdx.x * 128, n0 = blockIdx.y * 128;
    const int w = tid >> 6, lane = tid & 63;
    const int wm = w >> 1, wn = w & 1;
    const int frow = lane & 15, fk = (lane >> 4) * 8;

    f32x4 acc[4][4];
#pragma unroll
    for (int mi = 0; mi < 4; mi++)
#pragma unroll
        for (int ni = 0; ni < 4; ni++) acc[mi][ni] = (f32x4){0.f, 0.f, 0.f, 0.f};

    const int srow = tid >> 1;
    const int skq = (tid & 1) * 16;

    const unsigned short* gAhi = Ahi + (size_t)(m0 + srow) * CATK_ + skq;
    const unsigned short* gAlo = Alo + (size_t)(m0 + srow) * CATK_ + skq;
    const float*          gW   = W   + (size_t)(n0 + srow) * CATK_ + skq;

    int4 rAh0, rAh1, rAl0, rAl1;
    float4 rW0, rW1, rW2, rW3;

#define FC1_LOAD(kb)                                        \
    do {                                                    \
        rAh0 = *(const int4*)(gAhi + (kb));                 \
        rAh1 = *(const int4*)(gAhi + (kb) + 8);             \
        rAl0 = *(const int4*)(gAlo + (kb));                 \
        rAl1 = *(const int4*)(gAlo + (kb) + 8);             \
        rW0  = *(const float4*)(gW + (kb));                 \
        rW1  = *(const float4*)(gW + (kb) + 4);             \
        rW2  = *(const float4*)(gW + (kb) + 8);             \
        rW3  = *(const float4*)(gW + (kb) + 12);            \
    } while (0)

    FC1_LOAD(0);

    for (int kb = 0; kb < CATK_; kb += 32) {
        __syncthreads();
        *(int4*)&lA[0][srow][skq]     = rAh0;
        *(int4*)&lA[0][srow][skq + 8] = rAh1;
        *(int4*)&lA[1][srow][skq]     = rAl0;
        *(int4*)&lA[1][srow][skq + 8] = rAl1;
        {
            float f[16] = {rW0.x, rW0.y, rW0.z, rW0.w, rW1.x, rW1.y, rW1.z, rW1.w,
                           rW2.x, rW2.y, rW2.z, rW2.w, rW3.x, rW3.y, rW3.z, rW3.w};
            unsigned hp[8], lp[8];
#pragma unroll
            for (int j = 0; j < 8; j++) {
                float x0 = f[2 * j], x1 = f[2 * j + 1];
                unsigned short h0 = bf16_rne(x0), h1 = bf16_rne(x1);
                float r0 = x0 - __uint_as_float((unsigned)h0 << 16);
                float r1 = x1 - __uint_as_float((unsigned)h1 << 16);
                hp[j] = (unsigned)h0 | ((unsigned)h1 << 16);
                lp[j] = (unsigned)bf16_rne(r0) | ((unsigned)bf16_rne(r1) << 16);
            }
            *(int4*)&lW[0][srow][skq]     = make_int4(hp[0], hp[1], hp[2], hp[3]);
            *(int4*)&lW[0][srow][skq + 8] = make_int4(hp[4], hp[5], hp[6], hp[7]);
            *(int4*)&lW[1][srow][skq]     = make_int4(lp[0], lp[1], lp[2], lp[3]);
            *(int4*)&lW[1][srow][skq + 8] = make_int4(lp[4], lp[5], lp[6], lp[7]);
        }
        __syncthreads();
        if (kb + 32 < CATK_) FC1_LOAD(kb + 32);

        bf16x8 a[2][4];
#pragma unroll
        for (int mi = 0; mi < 4; mi++) {
            int r = wm * 64 + mi * 16 + frow;
            a[0][mi] = *(const bf16x8*)&lA[0][r][fk];
            a[1][mi] = *(const bf16x8*)&lA[1][r][fk];
        }
#pragma unroll
        for (int ni = 0; ni < 4; ni++) {
            int r = wn * 64 + ni * 16 + frow;
            bf16x8 bh = *(const bf16x8*)&lW[0][r][fk];
            bf16x8 bl = *(const bf16x8*)&lW[1][r][fk];
#pragma unroll
            for (int mi = 0; mi < 4; mi++) {
                acc[mi][ni] = __builtin_amdgcn_mfma_f32_16x16x32_bf16(a[0][mi], bh, acc[mi][ni], 0, 0, 0);
                acc[mi][ni] = __builtin_amdgcn_mfma_f32_16x16x32_bf16(a[1][mi], bh, acc[mi][ni], 0, 0, 0);
                acc[mi][ni] = __builtin_amdgcn_mfma_f32_16x16x32_bf16(a[0][mi], bl, acc[mi][ni], 0, 0, 0);
            }
        }
    }
#undef FC1_LOAD

#pragma unroll
    for (int ni = 0; ni < 4; ni++) {
        int col = n0 + wn * 64 + ni * 16 + frow;
        float bc = bias[col];
#pragma unroll
        for (int mi = 0; mi < 4; mi++) {
            int mbase = m0 + wm * 64 + mi * 16 + (lane >> 4) * 4;
            f32x4 v = acc[mi][ni];
#pragma unroll
            for (int r = 0; r < 4; r++) {
                int m = mbase + r;
                if (m < TD_ * B_) {
                    int tt = m >> 5, bb2 = m & 31;
                    C[((size_t)bb2 * T_ + tt) * V_ + col] = v[r] + bc;
                }
            }
        }
    }
}

// ---------------------------------------------------------------------------
__global__ __launch_bounds__(256)
void argmax_kernel(const float* __restrict__ outp, float* __restrict__ preds)
{
    int row = blockIdx.x;
    int t = row >> 5, b = row & 31;
    const float* p = outp + ((size_t)b * T_ + t) * V_;
    int tid = threadIdx.x;
    float best = -3.4e38f; int bi = V_;
    for (int i = tid; i < V_; i += 256) {
        float v = p[i];
        if (v > best) { best = v; bi = i; }
    }
    __shared__ float bv[256];
    __shared__ int bidx[256];
    bv[tid] = best; bidx[tid] = bi;
    __syncthreads();
    for (int off = 128; off > 0; off >>= 1) {
        if (tid < off) {
            float v2 = bv[tid + off]; int i2 = bidx[tid + off];
            if (v2 > bv[tid] || (v2 == bv[tid] && i2 < bidx[tid])) { bv[tid] = v2; bidx[tid] = i2; }
        }
        __syncthreads();
    }
    if (tid == 0) preds[(size_t)b * T_ + t] = (float)bidx[0];
}

// ---------------------------------------------------------------------------
__global__ __launch_bounds__(256)
void zero_tail_kernel(float* __restrict__ outp, float* __restrict__ preds)
{
    int tid = blockIdx.x * 256 + threadIdx.x;
    if (tid < B_ * V_) {
        int b = tid / V_;
        int c = tid % V_;
        outp[((size_t)b * T_ + (T_ - 1)) * V_ + c] = 0.f;
    }
    if (tid < B_) preds[(size_t)tid * T_ + (T_ - 1)] = 0.f;
}

// ---------------------------------------------------------------------------
extern "C" void kernel_launch(void* const* d_in, const int* in_sizes, int n_in,
                              void* d_out, int out_size, void* d_ws, size_t ws_size,
                              hipStream_t stream)
{
    (void)in_sizes; (void)n_in; (void)out_size;
    const int*   src     = (const int*)d_in[0];
    const int*   tgt     = (const int*)d_in[1];
    const float* enc_emb = (const float*)d_in[2];
    const float* Wih_f   = (const float*)d_in[3];
    const float* Whh_f   = (const float*)d_in[4];
    const float* bih_f   = (const float*)d_in[5];
    const float* bhh_f   = (const float*)d_in[6];
    const float* Wih_b   = (const float*)d_in[7];
    const float* Whh_b   = (const float*)d_in[8];
    const float* bih_b   = (const float*)d_in[9];
    const float* bhh_b   = (const float*)d_in[10];
    const float* fcW     = (const float*)d_in[11];
    const float* fcb     = (const float*)d_in[12];
    const float* dec_emb = (const float*)d_in[13];
    const float* attn_W  = (const float*)d_in[14];
    const float* attn_b  = (const float*)d_in[15];
    const float* attn_v  = (const float*)d_in[16];
    const float* dWih    = (const float*)d_in[17];
    const float* dWhh    = (const float*)d_in[18];
    const float* dbih    = (const float*)d_in[19];
    const float* dbhh    = (const float*)d_in[20];
    const float* fc1W    = (const float*)d_in[21];
    const float* fc1b    = (const float*)d_in[22];
    (void)dbih;

    // ws layout
    float* ws     = (float*)d_ws;
    float* cat    = ws;                                  // 3,612,672 f
    float* gx_emb = cat + (size_t)TD_ * B_ * CATK_;      // 3,096,576 f
    int*   tokf   = (int*)(gx_emb + (size_t)TD_ * B_ * G3_);
    int*   tokb   = tokf + 4096;
    int*   tokd   = tokb + 4096;
    unsigned* bars = (unsigned*)(tokd + 4096);           // 4096 u, 256B-aligned
    unsigned short* Ahi = (unsigned short*)(bars + 4096);
    unsigned short* Alo = Ahi + (size_t)MPAD_ * CATK_;
    size_t ws_req = (size_t)((char*)(Alo + (size_t)MPAD_ * CATK_) - (char*)d_ws);
    const bool use_mfma = (ws_size >= ws_req);

    // d_out scratch (fully overwritten by fc1 + zero_tail afterwards)
    float* dout      = (float*)d_out;
    float* gxf       = dout;                                        // 6,291,456
    float* gxb       = gxf + (size_t)S_ * B_ * G3_;                 // 6,291,456
    float* enc_bt    = gxb + (size_t)S_ * B_ * G3_;                 // 4,194,304
    float* enc_projB = enc_bt + (size_t)B_ * S_ * 2 * H_;           // 2,097,152
    float* hT        = enc_projB + (size_t)B_ * S_ * H_;            // 2 x 16,384 ([pp][b][k])
    float* hwhT      = hT + 2 * B_ * H_;                            // 16,384 ([b][k])
    float* wT        = hwhT + B_ * H_;                              // 32,768 ([b][c])
    float* h_enc     = wT + 2 * B_ * H_;                            // 4 x 16,384 ([dir][pp][b][k])
    float* preds     = dout + (size_t)B_ * T_ * V_;

    dim3 thr(256);

    hipLaunchKernelGGL(prep_kernel, dim3(256), thr, 0, stream,
                       src, tgt, tokf, tokb, tokd, h_enc, bars);
    hipLaunchKernelGGL(emb_cat_kernel, dim3(TD_ * B_), thr, 0, stream, tokd, dec_emb, cat);

    hipLaunchKernelGGL((gemm128_kernel<1, 0>), dim3(G3_ / 128, (S_ * B_) / 128), thr, 0, stream,
                       (const float*)nullptr, 0, tokf, enc_emb, Wih_f, E_, bih_f,
                       gxf, G3_, S_ * B_, G3_, E_);
    hipLaunchKernelGGL((gemm128_kernel<1, 0>), dim3(G3_ / 128, (S_ * B_) / 128), thr, 0, stream,
                       (const float*)nullptr, 0, tokb, enc_emb, Wih_b, E_, bih_b,
                       gxb, G3_, S_ * B_, G3_, E_);

    // encoder recurrence + enc_fc in ONE launch (128 blocks)
    hipLaunchKernelGGL(enc_coop_kernel, dim3(128), thr, 0, stream,
                       gxf, gxb, Whh_f, bhh_f, Whh_b, bhh_b, h_enc, enc_bt,
                       fcW, fcb, hT /* slot 0, [b][k] */, bars);

    hipLaunchKernelGGL((gemm128_kernel<0, 0>), dim3(H_ / 128, (B_ * S_) / 128), thr, 0, stream,
                       enc_bt, 2 * H_, (const int*)nullptr, (const float*)nullptr,
                       attn_W + H_, G3_, attn_b, enc_projB, H_, B_ * S_, H_, 2 * H_);

    hipLaunchKernelGGL((gemm128_kernel<1, 0>), dim3(G3_ / 128, (TD_ * B_ + 127) / 128), thr, 0, stream,
                       (const float*)nullptr, 0, tokd, dec_emb, dWih, DIN_, dbih,
                       gx_emb, G3_, TD_ * B_, G3_, E_);

    // decoder recurrence in ONE launch (128 blocks)
    hipLaunchKernelGGL(dec_coop_kernel, dim3(128), thr, 0, stream,
                       attn_W, attn_v, enc_projB, enc_bt, src,
                       dWhh, dbhh, dWih, gx_emb, cat, hT, hwhT, wT,
                       bars + 2048);

    if (use_mfma) {
        hipLaunchKernelGGL(splitA_kernel, dim3((MPAD_ * CATK_ / 4 + 255) / 256), thr, 0, stream,
                           cat, Ahi, Alo);
        hipLaunchKernelGGL(fc1_mfma_kernel, dim3(MPAD_ / 128, V_ / 128), thr, 0, stream,
                           Ahi, Alo, fc1W, fc1b, dout);
    } else {
        hipLaunchKernelGGL((gemm128_kernel<0, 1>), dim3(V_ / 128, (TD_ * B_ + 127) / 128), thr, 0, stream,
                           cat, CATK_, (const int*)nullptr, (const float*)nullptr,
                           fc1W, CATK_, fc1b, dout, V_, TD_ * B_, V_, CATK_);
    }

    hipLaunchKernelGGL(argmax_kernel, dim3(TD_ * B_), thr, 0, stream, dout, preds);
    hipLaunchKernelGGL(zero_tail_kernel, dim3((B_ * V_ + 255) / 256), thr, 0, stream, dout, preds);
}

// Round 10
// 6063.425 us; speedup vs baseline: 1.7581x; 1.7581x over previous
//
#include <hip/hip_runtime.h>

#define V_ 32000
#define E_ 256
#define H_ 512
#define B_ 32
#define S_ 128
#define T_ 64
#define TD_ 63        // decoder steps (T-1)
#define G3_ 1536      // 3*H
#define CATK_ 1792    // H + E + 2H
#define DIN_ 1280     // E + 2H
#define MPAD_ 2048    // padded M for fc1 MFMA

typedef __attribute__((ext_vector_type(8))) short bf16x8;
typedef __attribute__((ext_vector_type(4))) float f32x4;

__device__ inline unsigned short bf16_rne(float x) {
    unsigned u = __float_as_uint(x);
    unsigned r = u + 0x7FFFu + ((u >> 16) & 1u);
    return (unsigned short)(r >> 16);
}

// agent-scope ops: coherence-point access, no cache invalidation (r5-proven)
__device__ __forceinline__ float ato_ldf(const float* p) {
    return __hip_atomic_load((const float*)p, __ATOMIC_RELAXED, __HIP_MEMORY_SCOPE_AGENT);
}
__device__ __forceinline__ void ato_stf(float* p, float v) {
    __hip_atomic_store(p, v, __ATOMIC_RELAXED, __HIP_MEMORY_SCOPE_AGENT);
}

// ---------------------------------------------------------------------------
// Fence-free hierarchical barrier: groups of 16 blocks + top level.
// ---------------------------------------------------------------------------
__device__ __forceinline__ void fast_barN(unsigned* base, int idx, unsigned ngroups)
{
    asm volatile("s_waitcnt vmcnt(0)" ::: "memory");
    __syncthreads();
    if (threadIdx.x == 0) {
        unsigned* gcnt = base + (idx >> 4) * 64;
        unsigned* ggen = gcnt + 32;
        unsigned* tcnt = base + ngroups * 64;
        unsigned* tgen = tcnt + 32;
        unsigned g0 = __hip_atomic_load(ggen, __ATOMIC_RELAXED, __HIP_MEMORY_SCOPE_AGENT);
        unsigned a  = __hip_atomic_fetch_add(gcnt, 1u, __ATOMIC_RELAXED, __HIP_MEMORY_SCOPE_AGENT);
        if (a == 15u) {
            unsigned t0 = __hip_atomic_load(tgen, __ATOMIC_RELAXED, __HIP_MEMORY_SCOPE_AGENT);
            unsigned ta = __hip_atomic_fetch_add(tcnt, 1u, __ATOMIC_RELAXED, __HIP_MEMORY_SCOPE_AGENT);
            if (ta == ngroups - 1u) {
                __hip_atomic_store(tcnt, 0u, __ATOMIC_RELAXED, __HIP_MEMORY_SCOPE_AGENT);
                __hip_atomic_store(tgen, t0 + 1u, __ATOMIC_RELAXED, __HIP_MEMORY_SCOPE_AGENT);
            } else {
                while (__hip_atomic_load(tgen, __ATOMIC_RELAXED, __HIP_MEMORY_SCOPE_AGENT) == t0)
                    __builtin_amdgcn_s_sleep(1);
            }
            __hip_atomic_store(gcnt, 0u, __ATOMIC_RELAXED, __HIP_MEMORY_SCOPE_AGENT);
            __hip_atomic_store(ggen, g0 + 1u, __ATOMIC_RELAXED, __HIP_MEMORY_SCOPE_AGENT);
        } else {
            while (__hip_atomic_load(ggen, __ATOMIC_RELAXED, __HIP_MEMORY_SCOPE_AGENT) == g0)
                __builtin_amdgcn_s_sleep(1);
        }
    }
    __syncthreads();
}

// ---------------------------------------------------------------------------
__global__ __launch_bounds__(256)
void prep_kernel(const int* __restrict__ src, const int* __restrict__ tgt,
                 int* __restrict__ tokf, int* __restrict__ tokb, int* __restrict__ tokd,
                 float* __restrict__ enc_h0, unsigned* __restrict__ bars)
{
    int tid = blockIdx.x * 256 + threadIdx.x;
    if (tid < S_ * B_) {
        int s = tid >> 5, b = tid & 31;
        tokf[tid] = src[b * S_ + s];
        tokb[tid] = src[b * S_ + (S_ - 1 - s)];
    }
    if (tid < TD_ * B_) {
        int t = tid >> 5, b = tid & 31;
        tokd[tid] = tgt[b * T_ + t];
    }
    if (tid < 2 * B_ * H_) enc_h0[tid] = 0.f;   // encrot slot 0
    if (tid < 4096) bars[tid] = 0u;
}

// ---------------------------------------------------------------------------
__global__ __launch_bounds__(256)
void emb_cat_kernel(const int* __restrict__ tokd, const float* __restrict__ dec_emb,
                    float* __restrict__ cat)
{
    int row = blockIdx.x;          // row = t*32 + b
    int tid = threadIdx.x;         // 0..255 == E_
    cat[(size_t)row * CATK_ + H_ + tid] = dec_emb[(size_t)tokd[row] * E_ + tid];
}

// ---------------------------------------------------------------------------
// Generic fp32 GEMM (small GEMMs + fallback fc1)
// ---------------------------------------------------------------------------
template<int GATHER, int FC1MAP>
__global__ __launch_bounds__(256)
void gemm128_kernel(const float* __restrict__ A, int lda,
                    const int* __restrict__ tokens, const float* __restrict__ emb,
                    const float* __restrict__ W, int ldw,
                    const float* __restrict__ bias,
                    float* __restrict__ C, int ldc,
                    int M, int N, int K)
{
    __shared__ float As[16][132];
    __shared__ float Ws[16][132];
    (void)N;
    int tid = threadIdx.x;
    int m0 = blockIdx.y * 128, n0 = blockIdx.x * 128;
    int tx = tid & 15, ty = tid >> 4;
    float c[8][8];
#pragma unroll
    for (int i = 0; i < 8; i++)
#pragma unroll
        for (int j = 0; j < 8; j++) c[i][j] = 0.f;

    int arow = tid >> 1;
    int kq = (tid & 1) * 8;

    int am = m0 + arow; if (am >= M) am = M - 1;
    const float* arp;
    if (GATHER) arp = emb + (size_t)tokens[am] * (size_t)K;
    else        arp = A + (size_t)am * (size_t)lda;
    const float* wrp = W + (size_t)(n0 + arow) * (size_t)ldw;

    for (int kb = 0; kb < K; kb += 16) {
        __syncthreads();
        float4 a0 = *(const float4*)(arp + kb + kq);
        float4 a1 = *(const float4*)(arp + kb + kq + 4);
        float4 w0 = *(const float4*)(wrp + kb + kq);
        float4 w1 = *(const float4*)(wrp + kb + kq + 4);
        As[kq + 0][arow] = a0.x; As[kq + 1][arow] = a0.y;
        As[kq + 2][arow] = a0.z; As[kq + 3][arow] = a0.w;
        As[kq + 4][arow] = a1.x; As[kq + 5][arow] = a1.y;
        As[kq + 6][arow] = a1.z; As[kq + 7][arow] = a1.w;
        Ws[kq + 0][arow] = w0.x; Ws[kq + 1][arow] = w0.y;
        Ws[kq + 2][arow] = w0.z; Ws[kq + 3][arow] = w0.w;
        Ws[kq + 4][arow] = w1.x; Ws[kq + 5][arow] = w1.y;
        Ws[kq + 6][arow] = w1.z; Ws[kq + 7][arow] = w1.w;
        __syncthreads();
#pragma unroll
        for (int kk = 0; kk < 16; kk++) {
            float a[8], bb[8];
            *(float4*)&a[0]  = *(const float4*)&As[kk][ty * 8];
            *(float4*)&a[4]  = *(const float4*)&As[kk][ty * 8 + 4];
            *(float4*)&bb[0] = *(const float4*)&Ws[kk][tx * 8];
            *(float4*)&bb[4] = *(const float4*)&Ws[kk][tx * 8 + 4];
#pragma unroll
            for (int i = 0; i < 8; i++)
#pragma unroll
                for (int j = 0; j < 8; j++) c[i][j] += a[i] * bb[j];
        }
    }

#pragma unroll
    for (int i = 0; i < 8; i++) {
        int m = m0 + ty * 8 + i;
        if (m < M) {
            size_t rowoff;
            if (FC1MAP) { int tt = m >> 5, bb2 = m & 31; rowoff = ((size_t)bb2 * T_ + tt) * (size_t)ldc; }
            else        rowoff = (size_t)m * (size_t)ldc;
#pragma unroll
            for (int j = 0; j < 8; j += 4) {
                int n = n0 + tx * 8 + j;
                float4 v;
                v.x = c[i][j + 0] + bias[n + 0];
                v.y = c[i][j + 1] + bias[n + 1];
                v.z = c[i][j + 2] + bias[n + 2];
                v.w = c[i][j + 3] + bias[n + 3];
                *(float4*)(C + rowoff + n) = v;
            }
        }
    }
}

// ---------------------------------------------------------------------------
// PERSISTENT bi-GRU encoder (r8-exact): rotating h, cached reads, agent
// stores, per-dir 64-block barrier. Tail -> hT0 ([b][k] layout for dec).
// ---------------------------------------------------------------------------
__global__ __launch_bounds__(256)
void enc_coop_kernel(const float* __restrict__ gxf, const float* __restrict__ gxb,
                     const float* __restrict__ Whh_f, const float* __restrict__ bhh_f,
                     const float* __restrict__ Whh_b, const float* __restrict__ bhh_b,
                     float* __restrict__ encrot, float* __restrict__ enc_bt,
                     const float* __restrict__ fcW, const float* __restrict__ fcb,
                     float* __restrict__ hT0, unsigned* __restrict__ bars)
{
    const int bid = blockIdx.x;
    const int dir = bid >> 6, bh = (bid >> 5) & 1, kc = bid & 31;
    const int tid = threadIdx.x;
    const int bl = tid & 15, kl = tid >> 4;
    const int b = bh * 16 + bl, k = kc * 16 + kl;
    const float* Whh = dir ? Whh_b : Whh_f;
    const float* bhhp = dir ? bhh_b : bhh_f;
    const float* gx  = dir ? gxb : gxf;
    __shared__ float hL[16 * 516];
    const float* wr = Whh + (size_t)k * H_;
    const float* wz = Whh + (size_t)(H_ + k) * H_;
    const float* wn = Whh + (size_t)(2 * H_ + k) * H_;
    const float b_r = bhhp[k], b_z = bhhp[H_ + k], b_n = bhhp[2 * H_ + k];
    unsigned* dbar = bars + dir * 512;
    const int idx = bid & 63;

    for (int t = 0; t < S_; ++t) {
        const float* hin = encrot + (size_t)t * (2 * B_ * H_) + (size_t)dir * (B_ * H_);
        float* hout = encrot + (size_t)(t + 1) * (2 * B_ * H_) + (size_t)dir * (B_ * H_);
        const float* hsrc = hin + (size_t)bh * 16 * H_;
        for (int i = tid * 4; i < 16 * H_; i += 1024) {
            int r = i >> 9, cix = i & 511;
            *(float4*)&hL[r * 516 + cix] = *(const float4*)(hsrc + i);
        }
        __syncthreads();
        float ar = 0.f, az = 0.f, an = 0.f;
        const float* hv = &hL[bl * 516];
#pragma unroll 4
        for (int j = 0; j < H_; j += 4) {
            float4 h4 = *(const float4*)(hv + j);
            float4 r4 = *(const float4*)(wr + j);
            float4 z4 = *(const float4*)(wz + j);
            float4 n4 = *(const float4*)(wn + j);
            ar += h4.x * r4.x + h4.y * r4.y + h4.z * r4.z + h4.w * r4.w;
            az += h4.x * z4.x + h4.y * z4.y + h4.z * z4.z + h4.w * z4.w;
            an += h4.x * n4.x + h4.y * n4.y + h4.z * n4.z + h4.w * n4.w;
        }
        const float* gxr = gx + ((size_t)t * B_ + b) * G3_;
        float xr = gxr[k], xz = gxr[H_ + k], xn = gxr[2 * H_ + k];
        float rg = 1.f / (1.f + expf(-(xr + ar + b_r)));
        float zg = 1.f / (1.f + expf(-(xz + az + b_z)));
        float ng = tanhf(xn + rg * (an + b_n));
        float hp = hL[bl * 516 + k];
        float h2 = (1.f - zg) * ng + zg * hp;
        ato_stf(hout + (size_t)b * H_ + k, h2);
        int s_out = dir ? (S_ - 1 - t) : t;
        enc_bt[((size_t)b * S_ + s_out) * (2 * H_) + dir * H_ + k] = h2;
        fast_barN(dbar, idx, 4);
    }
    fast_barN(bars + 1024, bid, 8);    // both dirs done

    // tail: hidden = tanh([hf,hb] @ fcW.T + fcb) -> hT0[b][k]
    {
        const int b2 = bid & 31, ih = bid >> 5;
        float* hc = hL;
        const float* hfin = encrot + (size_t)S_ * (2 * B_ * H_);
        const float* hf  = hfin + (size_t)b2 * H_;
        const float* hbk = hfin + (size_t)B_ * H_ + (size_t)b2 * H_;
        for (int i = tid; i < H_; i += 256) { hc[i] = hf[i]; hc[H_ + i] = hbk[i]; }
        __syncthreads();
        if (tid < 128) {
            int i = ih * 128 + tid;
            const float* w = fcW + (size_t)i * (2 * H_);
            float acc = 0.f;
            for (int j = 0; j < 2 * H_; j += 4) {
                float4 a4 = *(const float4*)&hc[j];
                float4 w4 = *(const float4*)(w + j);
                acc += a4.x * w4.x + a4.y * w4.y + a4.z * w4.z + a4.w * w4.w;
            }
            ato_stf(hT0 + (size_t)b2 * H_ + i, tanhf(acc + fcb[i]));
        }
    }
}

// ---------------------------------------------------------------------------
// PERSISTENT attention decoder v10: 256 blocks = (bp 16) x (kr 16), 4 phases.
// k-slice = 32 k per block; batches {2bp, 2bp+1}.
// P0 (all): h cols (atomics) -> hwh (32 W_h rows -> global) + ghh (96 rows, LDS).
// P1 (kr<8): attention s-QUARTER (q=kr&3, b=2bp+(kr>>2)): scores -> online
//     softmax partial (m,l) + wpart[1024] -> global atomics. 4-way ILP streams.
// P1b (kr==8,9): combine 4 quarters (exact online-softmax merge) -> wT + cat.
// P2 (all): w cols (atomics) -> xw (96 Wih rows, LDS) -> gates -> h' + cat.
// ---------------------------------------------------------------------------
__global__ __launch_bounds__(256)
void dec_coop_kernel(const float* __restrict__ attn_W, const float* __restrict__ attn_v,
                     const float* __restrict__ enc_projB, const float* __restrict__ enc_bt,
                     const int* __restrict__ src,
                     const float* __restrict__ dWhh, const float* __restrict__ dbhh,
                     const float* __restrict__ dWih, const float* __restrict__ gx_emb,
                     float* __restrict__ cat, float* __restrict__ hT,
                     float* __restrict__ hwhT, float* __restrict__ wT,
                     float* __restrict__ wpart, float* __restrict__ mlq,
                     unsigned* __restrict__ bars)
{
    const int bid = blockIdx.x, tid = threadIdx.x;
    const int bp = bid >> 4, kr = bid & 15;
    const int b0 = bp * 2, b1 = b0 + 1;
    const int k0 = kr * 32;
    __shared__ float hA[512], hB[512];
    __shared__ float ghhA[96], ghhB[96];
    __shared__ float xwA[96], xwB[96];
    __shared__ float wA[1024], wB[1024];
    __shared__ float hwhL[512], vL[512], sL[32], eS[32], cmb[8];

    const int p1act = (kr < 8);
    const int p1q   = kr & 3;
    const int p1b_  = b0 + (kr >> 2);          // batch if P1-active
    const int cact  = (kr == 8 || kr == 9);
    const int cb    = b0 + (kr - 8);           // batch if P1b-active
    const int r0 = tid >> 1, b2_0 = tid & 1;   // P0 task

    for (int t = 0; t < TD_; ++t) {
        const int pp = t & 1;
        const float* hin = hT + (size_t)pp * (B_ * H_);
        float* hout = hT + (size_t)(1 - pp) * (B_ * H_);
        float* cat_t = cat + (size_t)t * B_ * CATK_;

        // ---- P0: hwh (global) + ghh (LDS-local) ----
        for (int j = tid; j < H_; j += 256) {
            hA[j] = ato_ldf(hin + (size_t)b0 * H_ + j);
            hB[j] = ato_ldf(hin + (size_t)b1 * H_ + j);
        }
        __syncthreads();
        {
            const float* hv = b2_0 ? hB : hA;
            const float* wrow;
            if (r0 < 32) wrow = attn_W + (size_t)(k0 + r0) * G3_;
            else {
                int rr = r0 - 32;
                wrow = dWhh + (size_t)((rr >> 5) * H_ + k0 + (rr & 31)) * H_;
            }
            float a0 = 0.f, a1 = 0.f;
            for (int j = 0; j < H_; j += 8) {
                float4 w0 = *(const float4*)(wrow + j);
                float4 w1 = *(const float4*)(wrow + j + 4);
                float4 h0 = *(const float4*)&hv[j];
                float4 h1 = *(const float4*)&hv[j + 4];
                a0 += w0.x * h0.x + w0.y * h0.y + w0.z * h0.z + w0.w * h0.w;
                a1 += w1.x * h1.x + w1.y * h1.y + w1.z * h1.z + w1.w * h1.w;
            }
            float acc = a0 + a1;
            int b = b2_0 ? b1 : b0;
            if (r0 < 32) ato_stf(hwhT + (size_t)b * H_ + k0 + r0, acc);
            else {
                int rr = r0 - 32;
                float* g = b2_0 ? ghhB : ghhA;
                g[rr] = acc + dbhh[(rr >> 5) * H_ + k0 + (rr & 31)];
            }
        }
        fast_barN(bars, bid, 16);

        // ---- P1: scores + online-softmax partial + wpart (s-quarter) ----
        if (p1act) {
            const int ab = p1b_;
            const int s0 = p1q * 32;
            for (int i = tid; i < H_; i += 256) {
                hwhL[i] = ato_ldf(hwhT + (size_t)ab * H_ + i);
                vL[i] = attn_v[i];
            }
            __syncthreads();
            {
                int s = tid >> 3, u = tid & 7;
                const float* pr = enc_projB + ((size_t)ab * S_ + s0 + s) * H_ + u * 64;
                const float* hwo = hwhL + u * 64;
                const float* vo = vL + u * 64;
                float a0 = 0.f, a1 = 0.f, a2 = 0.f, a3 = 0.f;
#pragma unroll
                for (int i = 0; i < 64; i += 4) {
                    float x0 = hwo[i + 0] + pr[i + 0];
                    float x1 = hwo[i + 1] + pr[i + 1];
                    float x2 = hwo[i + 2] + pr[i + 2];
                    float x3 = hwo[i + 3] + pr[i + 3];
                    a0 += vo[i + 0] * (1.f - 2.f / (__expf(2.f * x0) + 1.f));
                    a1 += vo[i + 1] * (1.f - 2.f / (__expf(2.f * x1) + 1.f));
                    a2 += vo[i + 2] * (1.f - 2.f / (__expf(2.f * x2) + 1.f));
                    a3 += vo[i + 3] * (1.f - 2.f / (__expf(2.f * x3) + 1.f));
                }
                float acc = (a0 + a1) + (a2 + a3);
                acc += __shfl_xor(acc, 1);
                acc += __shfl_xor(acc, 2);
                acc += __shfl_xor(acc, 4);
                if (u == 0) sL[s] = (src[ab * S_ + s0 + s] != 0) ? acc : -1e10f;
            }
            __syncthreads();
            if (tid < 32) {
                float v = sL[tid];
                float m = v;
#pragma unroll
                for (int off = 1; off < 32; off <<= 1) m = fmaxf(m, __shfl_xor(m, off));
                float e = expf(v - m);
                eS[tid] = e;
                float l = e;
#pragma unroll
                for (int off = 1; off < 32; off <<= 1) l += __shfl_xor(l, off);
                if (tid == 0) {
                    ato_stf(mlq + (size_t)(ab * 4 + p1q) * 2 + 0, m);
                    ato_stf(mlq + (size_t)(ab * 4 + p1q) * 2 + 1, l);
                }
            }
            __syncthreads();
            {
                int c4 = tid * 4;
                const float* eb = enc_bt + ((size_t)ab * S_ + s0) * (2 * H_) + c4;
                float4 ac0 = {0, 0, 0, 0}, ac1 = {0, 0, 0, 0};
                float4 ac2 = {0, 0, 0, 0}, ac3 = {0, 0, 0, 0};
                for (int s = 0; s < 32; s += 4) {
                    float4 v0 = *(const float4*)(eb + (size_t)(s + 0) * (2 * H_));
                    float4 v1 = *(const float4*)(eb + (size_t)(s + 1) * (2 * H_));
                    float4 v2 = *(const float4*)(eb + (size_t)(s + 2) * (2 * H_));
                    float4 v3 = *(const float4*)(eb + (size_t)(s + 3) * (2 * H_));
                    float e0 = eS[s], e1 = eS[s + 1], e2 = eS[s + 2], e3 = eS[s + 3];
                    ac0.x += e0 * v0.x; ac0.y += e0 * v0.y; ac0.z += e0 * v0.z; ac0.w += e0 * v0.w;
                    ac1.x += e1 * v1.x; ac1.y += e1 * v1.y; ac1.z += e1 * v1.z; ac1.w += e1 * v1.w;
                    ac2.x += e2 * v2.x; ac2.y += e2 * v2.y; ac2.z += e2 * v2.z; ac2.w += e2 * v2.w;
                    ac3.x += e3 * v3.x; ac3.y += e3 * v3.y; ac3.z += e3 * v3.z; ac3.w += e3 * v3.w;
                }
                float* dst = wpart + (size_t)(ab * 4 + p1q) * 1024 + c4;
                ato_stf(dst + 0, (ac0.x + ac1.x) + (ac2.x + ac3.x));
                ato_stf(dst + 1, (ac0.y + ac1.y) + (ac2.y + ac3.y));
                ato_stf(dst + 2, (ac0.z + ac1.z) + (ac2.z + ac3.z));
                ato_stf(dst + 3, (ac0.w + ac1.w) + (ac2.w + ac3.w));
            }
        }
        fast_barN(bars, bid, 16);

        // ---- P1b: combine quarters -> wT + cat w-cols ----
        if (cact) {
            const int ab = cb;
            if (tid < 4) {
                cmb[tid] = ato_ldf(mlq + (size_t)(ab * 4 + tid) * 2 + 0);
                cmb[4 + tid] = ato_ldf(mlq + (size_t)(ab * 4 + tid) * 2 + 1);
            }
            __syncthreads();
            float m = fmaxf(fmaxf(cmb[0], cmb[1]), fmaxf(cmb[2], cmb[3]));
            float e0 = expf(cmb[0] - m), e1 = expf(cmb[1] - m);
            float e2 = expf(cmb[2] - m), e3 = expf(cmb[3] - m);
            float L = e0 * cmb[4] + e1 * cmb[5] + e2 * cmb[6] + e3 * cmb[7];
            float inv = 1.f / L;
            int c4 = tid * 4;
            const float* p0 = wpart + (size_t)(ab * 4 + 0) * 1024 + c4;
            const float* p1 = wpart + (size_t)(ab * 4 + 1) * 1024 + c4;
            const float* p2 = wpart + (size_t)(ab * 4 + 2) * 1024 + c4;
            const float* p3 = wpart + (size_t)(ab * 4 + 3) * 1024 + c4;
            float4 w4;
            w4.x = (e0 * ato_ldf(p0 + 0) + e1 * ato_ldf(p1 + 0) + e2 * ato_ldf(p2 + 0) + e3 * ato_ldf(p3 + 0)) * inv;
            w4.y = (e0 * ato_ldf(p0 + 1) + e1 * ato_ldf(p1 + 1) + e2 * ato_ldf(p2 + 1) + e3 * ato_ldf(p3 + 1)) * inv;
            w4.z = (e0 * ato_ldf(p0 + 2) + e1 * ato_ldf(p1 + 2) + e2 * ato_ldf(p2 + 2) + e3 * ato_ldf(p3 + 2)) * inv;
            w4.w = (e0 * ato_ldf(p0 + 3) + e1 * ato_ldf(p1 + 3) + e2 * ato_ldf(p2 + 3) + e3 * ato_ldf(p3 + 3)) * inv;
            ato_stf(wT + (size_t)ab * 1024 + c4 + 0, w4.x);
            ato_stf(wT + (size_t)ab * 1024 + c4 + 1, w4.y);
            ato_stf(wT + (size_t)ab * 1024 + c4 + 2, w4.z);
            ato_stf(wT + (size_t)ab * 1024 + c4 + 3, w4.w);
            *(float4*)(cat_t + (size_t)ab * CATK_ + (H_ + E_) + c4) = w4;
        }
        fast_barN(bars, bid, 16);

        // ---- P2: xw (LDS-local) -> gates -> h' + cat ----
        for (int c = tid; c < 2 * H_; c += 256) {
            wA[c] = ato_ldf(wT + (size_t)b0 * 1024 + c);
            wB[c] = ato_ldf(wT + (size_t)b1 * 1024 + c);
        }
        __syncthreads();
        if (tid < 192) {
            int rr = tid >> 1, b2 = tid & 1;
            const float* wv = b2 ? wB : wA;
            const float* wrow = dWih + (size_t)((rr >> 5) * H_ + k0 + (rr & 31)) * DIN_ + E_;
            float a0 = 0.f, a1 = 0.f;
            for (int c = 0; c < 2 * H_; c += 8) {
                float4 w0 = *(const float4*)(wrow + c);
                float4 w1 = *(const float4*)(wrow + c + 4);
                float4 x0 = *(const float4*)&wv[c];
                float4 x1 = *(const float4*)&wv[c + 4];
                a0 += w0.x * x0.x + w0.y * x0.y + w0.z * x0.z + w0.w * x0.w;
                a1 += w1.x * x1.x + w1.y * x1.y + w1.z * x1.z + w1.w * x1.w;
            }
            (b2 ? xwB : xwA)[rr] = a0 + a1;
        }
        __syncthreads();
        if (tid < 64) {
            int b2 = tid >> 5, kk = tid & 31;
            int b = b2 ? b1 : b0;
            int k = k0 + kk;
            const float* g = b2 ? ghhB : ghhA;
            const float* x = b2 ? xwB : xwA;
            float hr = g[kk], hz = g[32 + kk], hn = g[64 + kk];
            float xr = x[kk], xz = x[32 + kk], xn = x[64 + kk];
            const float* gxe = gx_emb + ((size_t)t * B_ + b) * G3_;
            float rg = 1.f / (1.f + expf(-(gxe[k] + xr + hr)));
            float zg = 1.f / (1.f + expf(-(gxe[H_ + k] + xz + hz)));
            float ng = tanhf(gxe[2 * H_ + k] + xn + rg * hn);
            float hp = b2 ? hB[k] : hA[k];
            float h2 = (1.f - zg) * ng + zg * hp;
            ato_stf(hout + (size_t)b * H_ + k, h2);
            cat_t[(size_t)b * CATK_ + k] = h2;
        }
        fast_barN(bars, bid, 16);
    }
}

// ---------------------------------------------------------------------------
__global__ __launch_bounds__(256)
void splitA_kernel(const float* __restrict__ cat,
                   unsigned short* __restrict__ Ahi, unsigned short* __restrict__ Alo)
{
    size_t i4 = ((size_t)blockIdx.x * 256 + threadIdx.x) * 4;
    if (i4 >= (size_t)MPAD_ * CATK_) return;
    size_t row = i4 / CATK_;
    float4 v;
    if (row < (size_t)TD_ * B_) v = *(const float4*)(cat + i4);
    else { v.x = v.y = v.z = v.w = 0.f; }
    float f[4] = {v.x, v.y, v.z, v.w};
    unsigned short h[4], l[4];
#pragma unroll
    for (int j = 0; j < 4; j++) {
        h[j] = bf16_rne(f[j]);
        float hf = __uint_as_float((unsigned)h[j] << 16);
        l[j] = bf16_rne(f[j] - hf);
    }
    *(ushort4*)(Ahi + i4) = make_ushort4(h[0], h[1], h[2], h[3]);
    *(ushort4*)(Alo + i4) = make_ushort4(l[0], l[1], l[2], l[3]);
}

// ---------------------------------------------------------------------------
__global__ __launch_bounds__(256)
void fc1_mfma_kernel(const unsigned short* __restrict__ Ahi,
                     const unsigned short* __restrict__ Alo,
                     const float* __restrict__ W,
                     const float* __restrict__ bias,
                     float* __restrict__ C)
{
    __shared__ unsigned short lA[2][128][40];
    __shared__ unsigned short lW[2][128][40];
    const int tid = threadIdx.x;
    const int m0 = blockIdx.x * 128, n0 = blockIdx.y * 128;
    const int w = tid >> 6, lane = tid & 63;
    const int wm = w >> 1, wn = w & 1;
    const int frow = lane & 15, fk = (lane >> 4) * 8;

    f32x4 acc[4][4];
#pragma unroll
    for (int mi = 0; mi < 4; mi++)
#pragma unroll
        for (int ni = 0; ni < 4; ni++) acc[mi][ni] = (f32x4){0.f, 0.f, 0.f, 0.f};

    const int srow = tid >> 1;
    const int skq = (tid & 1) * 16;

    const unsigned short* gAhi = Ahi + (size_t)(m0 + srow) * CATK_ + skq;
    const unsigned short* gAlo = Alo + (size_t)(m0 + srow) * CATK_ + skq;
    const float*          gW   = W   + (size_t)(n0 + srow) * CATK_ + skq;

    int4 rAh0, rAh1, rAl0, rAl1;
    float4 rW0, rW1, rW2, rW3;

#define FC1_LOAD(kb)                                        \
    do {                                                    \
        rAh0 = *(const int4*)(gAhi + (kb));                 \
        rAh1 = *(const int4*)(gAhi + (kb) + 8);             \
        rAl0 = *(const int4*)(gAlo + (kb));                 \
        rAl1 = *(const int4*)(gAlo + (kb) + 8);             \
        rW0  = *(const float4*)(gW + (kb));                 \
        rW1  = *(const float4*)(gW + (kb) + 4);             \
        rW2  = *(const float4*)(gW + (kb) + 8);             \
        rW3  = *(const float4*)(gW + (kb) + 12);            \
    } while (0)

    FC1_LOAD(0);

    for (int kb = 0; kb < CATK_; kb += 32) {
        __syncthreads();
        *(int4*)&lA[0][srow][skq]     = rAh0;
        *(int4*)&lA[0][srow][skq + 8] = rAh1;
        *(int4*)&lA[1][srow][skq]     = rAl0;
        *(int4*)&lA[1][srow][skq + 8] = rAl1;
        {
            float f[16] = {rW0.x, rW0.y, rW0.z, rW0.w, rW1.x, rW1.y, rW1.z, rW1.w,
                           rW2.x, rW2.y, rW2.z, rW2.w, rW3.x, rW3.y, rW3.z, rW3.w};
            unsigned hp[8], lp[8];
#pragma unroll
            for (int j = 0; j < 8; j++) {
                float x0 = f[2 * j], x1 = f[2 * j + 1];
                unsigned short h0 = bf16_rne(x0), h1 = bf16_rne(x1);
                float r0 = x0 - __uint_as_float((unsigned)h0 << 16);
                float r1 = x1 - __uint_as_float((unsigned)h1 << 16);
                hp[j] = (unsigned)h0 | ((unsigned)h1 << 16);
                lp[j] = (unsigned)bf16_rne(r0) | ((unsigned)bf16_rne(r1) << 16);
            }
            *(int4*)&lW[0][srow][skq]     = make_int4(hp[0], hp[1], hp[2], hp[3]);
            *(int4*)&lW[0][srow][skq + 8] = make_int4(hp[4], hp[5], hp[6], hp[7]);
            *(int4*)&lW[1][srow][skq]     = make_int4(lp[0], lp[1], lp[2], lp[3]);
            *(int4*)&lW[1][srow][skq + 8] = make_int4(lp[4], lp[5], lp[6], lp[7]);
        }
        __syncthreads();
        if (kb + 32 < CATK_) FC1_LOAD(kb + 32);

        bf16x8 a[2][4];
#pragma unroll
        for (int mi = 0; mi < 4; mi++) {
            int r = wm * 64 + mi * 16 + frow;
            a[0][mi] = *(const bf16x8*)&lA[0][r][fk];
            a[1][mi] = *(const bf16x8*)&lA[1][r][fk];
        }
#pragma unroll
        for (int ni = 0; ni < 4; ni++) {
            int r = wn * 64 + ni * 16 + frow;
            bf16x8 bh = *(const bf16x8*)&lW[0][r][fk];
            bf16x8 bl = *(const bf16x8*)&lW[1][r][fk];
#pragma unroll
            for (int mi = 0; mi < 4; mi++) {
                acc[mi][ni] = __builtin_amdgcn_mfma_f32_16x16x32_bf16(a[0][mi], bh, acc[mi][ni], 0, 0, 0);
                acc[mi][ni] = __builtin_amdgcn_mfma_f32_16x16x32_bf16(a[1][mi], bh, acc[mi][ni], 0, 0, 0);
                acc[mi][ni] = __builtin_amdgcn_mfma_f32_16x16x32_bf16(a[0][mi], bl, acc[mi][ni], 0, 0, 0);
            }
        }
    }
#undef FC1_LOAD

#pragma unroll
    for (int ni = 0; ni < 4; ni++) {
        int col = n0 + wn * 64 + ni * 16 + frow;
        float bc = bias[col];
#pragma unroll
        for (int mi = 0; mi < 4; mi++) {
            int mbase = m0 + wm * 64 + mi * 16 + (lane >> 4) * 4;
            f32x4 v = acc[mi][ni];
#pragma unroll
            for (int r = 0; r < 4; r++) {
                int m = mbase + r;
                if (m < TD_ * B_) {
                    int tt = m >> 5, bb2 = m & 31;
                    C[((size_t)bb2 * T_ + tt) * V_ + col] = v[r] + bc;
                }
            }
        }
    }
}

// ---------------------------------------------------------------------------
__global__ __launch_bounds__(256)
void argmax_kernel(const float* __restrict__ outp, float* __restrict__ preds)
{
    int row = blockIdx.x;
    int t = row >> 5, b = row & 31;
    const float* p = outp + ((size_t)b * T_ + t) * V_;
    int tid = threadIdx.x;
    float best = -3.4e38f; int bi = V_;
    for (int i = tid; i < V_; i += 256) {
        float v = p[i];
        if (v > best) { best = v; bi = i; }
    }
    __shared__ float bv[256];
    __shared__ int bidx[256];
    bv[tid] = best; bidx[tid] = bi;
    __syncthreads();
    for (int off = 128; off > 0; off >>= 1) {
        if (tid < off) {
            float v2 = bv[tid + off]; int i2 = bidx[tid + off];
            if (v2 > bv[tid] || (v2 == bv[tid] && i2 < bidx[tid])) { bv[tid] = v2; bidx[tid] = i2; }
        }
        __syncthreads();
    }
    if (tid == 0) preds[(size_t)b * T_ + t] = (float)bidx[0];
}

// ---------------------------------------------------------------------------
__global__ __launch_bounds__(256)
void zero_tail_kernel(float* __restrict__ outp, float* __restrict__ preds)
{
    int tid = blockIdx.x * 256 + threadIdx.x;
    if (tid < B_ * V_) {
        int b = tid / V_;
        int c = tid % V_;
        outp[((size_t)b * T_ + (T_ - 1)) * V_ + c] = 0.f;
    }
    if (tid < B_) preds[(size_t)tid * T_ + (T_ - 1)] = 0.f;
}

// ---------------------------------------------------------------------------
extern "C" void kernel_launch(void* const* d_in, const int* in_sizes, int n_in,
                              void* d_out, int out_size, void* d_ws, size_t ws_size,
                              hipStream_t stream)
{
    (void)in_sizes; (void)n_in; (void)out_size;
    const int*   src     = (const int*)d_in[0];
    const int*   tgt     = (const int*)d_in[1];
    const float* enc_emb = (const float*)d_in[2];
    const float* Wih_f   = (const float*)d_in[3];
    const float* Whh_f   = (const float*)d_in[4];
    const float* bih_f   = (const float*)d_in[5];
    const float* bhh_f   = (const float*)d_in[6];
    const float* Wih_b   = (const float*)d_in[7];
    const float* Whh_b   = (const float*)d_in[8];
    const float* bih_b   = (const float*)d_in[9];
    const float* bhh_b   = (const float*)d_in[10];
    const float* fcW     = (const float*)d_in[11];
    const float* fcb     = (const float*)d_in[12];
    const float* dec_emb = (const float*)d_in[13];
    const float* attn_W  = (const float*)d_in[14];
    const float* attn_b  = (const float*)d_in[15];
    const float* attn_v  = (const float*)d_in[16];
    const float* dWih    = (const float*)d_in[17];
    const float* dWhh    = (const float*)d_in[18];
    const float* dbih    = (const float*)d_in[19];
    const float* dbhh    = (const float*)d_in[20];
    const float* fc1W    = (const float*)d_in[21];
    const float* fc1b    = (const float*)d_in[22];
    (void)dbih;

    // ws layout
    float* ws     = (float*)d_ws;
    float* cat    = ws;                                  // 3,612,672 f
    float* gx_emb = cat + (size_t)TD_ * B_ * CATK_;      // 3,096,576 f
    int*   tokf   = (int*)(gx_emb + (size_t)TD_ * B_ * G3_);
    int*   tokb   = tokf + 4096;
    int*   tokd   = tokb + 4096;
    unsigned* bars = (unsigned*)(tokd + 4096);           // 4096 u, 256B-aligned
    unsigned short* Ahi = (unsigned short*)(bars + 4096);
    unsigned short* Alo = Ahi + (size_t)MPAD_ * CATK_;
    size_t ws_req = (size_t)((char*)(Alo + (size_t)MPAD_ * CATK_) - (char*)d_ws);
    const bool use_mfma = (ws_size >= ws_req);

    // d_out scratch (fully overwritten by fc1 + zero_tail afterwards)
    float* dout      = (float*)d_out;
    float* gxf       = dout;                                        // 6,291,456
    float* gxb       = gxf + (size_t)S_ * B_ * G3_;                 // 6,291,456
    float* enc_bt    = gxb + (size_t)S_ * B_ * G3_;                 // 4,194,304
    float* enc_projB = enc_bt + (size_t)B_ * S_ * 2 * H_;           // 2,097,152
    float* encrot    = enc_projB + (size_t)B_ * S_ * H_;            // 129 x 32,768
    float* hT        = encrot + (size_t)(S_ + 1) * 2 * B_ * H_;     // 2 x 16,384 ([pp][b][k])
    float* hwhT      = hT + 2 * B_ * H_;                            // 16,384 ([b][k])
    float* wT        = hwhT + B_ * H_;                              // 32,768 ([b][c])
    float* wpart     = wT + 2 * B_ * H_;                            // 131,072 ([b][q][1024])
    float* mlq       = wpart + (size_t)B_ * 4 * 1024;               // 256
    float* preds     = dout + (size_t)B_ * T_ * V_;

    dim3 thr(256);

    hipLaunchKernelGGL(prep_kernel, dim3(256), thr, 0, stream,
                       src, tgt, tokf, tokb, tokd, encrot, bars);
    hipLaunchKernelGGL(emb_cat_kernel, dim3(TD_ * B_), thr, 0, stream, tokd, dec_emb, cat);

    hipLaunchKernelGGL((gemm128_kernel<1, 0>), dim3(G3_ / 128, (S_ * B_) / 128), thr, 0, stream,
                       (const float*)nullptr, 0, tokf, enc_emb, Wih_f, E_, bih_f,
                       gxf, G3_, S_ * B_, G3_, E_);
    hipLaunchKernelGGL((gemm128_kernel<1, 0>), dim3(G3_ / 128, (S_ * B_) / 128), thr, 0, stream,
                       (const float*)nullptr, 0, tokb, enc_emb, Wih_b, E_, bih_b,
                       gxb, G3_, S_ * B_, G3_, E_);

    // encoder recurrence + enc_fc in ONE launch (128 blocks, r8-exact)
    hipLaunchKernelGGL(enc_coop_kernel, dim3(128), thr, 0, stream,
                       gxf, gxb, Whh_f, bhh_f, Whh_b, bhh_b, encrot, enc_bt,
                       fcW, fcb, hT /* slot 0, [b][k] */, bars);

    hipLaunchKernelGGL((gemm128_kernel<0, 0>), dim3(H_ / 128, (B_ * S_) / 128), thr, 0, stream,
                       enc_bt, 2 * H_, (const int*)nullptr, (const float*)nullptr,
                       attn_W + H_, G3_, attn_b, enc_projB, H_, B_ * S_, H_, 2 * H_);

    hipLaunchKernelGGL((gemm128_kernel<1, 0>), dim3(G3_ / 128, (TD_ * B_ + 127) / 128), thr, 0, stream,
                       (const float*)nullptr, 0, tokd, dec_emb, dWih, DIN_, dbih,
                       gx_emb, G3_, TD_ * B_, G3_, E_);

    // decoder recurrence in ONE launch (256 blocks)
    hipLaunchKernelGGL(dec_coop_kernel, dim3(256), thr, 0, stream,
                       attn_W, attn_v, enc_projB, enc_bt, src,
                       dWhh, dbhh, dWih, gx_emb, cat, hT, hwhT, wT, wpart, mlq,
                       bars + 2048);

    if (use_mfma) {
        hipLaunchKernelGGL(splitA_kernel, dim3((MPAD_ * CATK_ / 4 + 255) / 256), thr, 0, stream,
                           cat, Ahi, Alo);
        hipLaunchKernelGGL(fc1_mfma_kernel, dim3(MPAD_ / 128, V_ / 128), thr, 0, stream,
                           Ahi, Alo, fc1W, fc1b, dout);
    } else {
        hipLaunchKernelGGL((gemm128_kernel<0, 1>), dim3(V_ / 128, (TD_ * B_ + 127) / 128), thr, 0, stream,
                           cat, CATK_, (const int*)nullptr, (const float*)nullptr,
                           fc1W, CATK_, fc1b, dout, V_, TD_ * B_, V_, CATK_);
    }

    hipLaunchKernelGGL(argmax_kernel, dim3(TD_ * B_), thr, 0, stream, dout, preds);
    hipLaunchKernelGGL(zero_tail_kernel, dim3((B_ * V_ + 255) / 256), thr, 0, stream, dout, preds);
}